// Round 2
// baseline (57.233 us; speedup 1.0000x reference)
//
#include <hip/hip_runtime.h>

// EdgeConsistencyLoss: mean((|∇edit| - |∇src|)^2) with Sobel 3x3, SAME zero pad.
// Shapes: [B=16, C=8, H=512, W=512] fp32 -> 128 independent 512x512 images.
//
// R1: ROWS 32->16 (4096 blocks, 2 waves each = 8192 waves = 100% occupancy cap;
//     was 50%). rocprof R0: Occupancy 42%, VALUBusy 24% -> latency-bound.

#define EPS 1e-8f

constexpr int W_DIM  = 512;
constexpr int H_DIM  = 512;
constexpr int NIMG   = 128;           // B*C
constexpr int ROWS   = 16;            // rows per block chunk
constexpr int CHUNKS = H_DIM / ROWS;  // 32
constexpr int TPB    = 128;           // threads per block; 4 columns per thread
constexpr int NBLK   = NIMG * CHUNKS; // 4096
constexpr double TOTAL_ELEMS = 33554432.0; // 16*8*512*512

__global__ __launch_bounds__(TPB) void edge_loss_stage1(
    const float* __restrict__ src, const float* __restrict__ edt,
    float* __restrict__ partial)
{
    const int blk   = blockIdx.x;
    const int n     = blk / CHUNKS;
    const int chunk = blk % CHUNKS;
    const int r0    = chunk * ROWS;
    const float* sbase = src + (size_t)n * H_DIM * W_DIM;
    const float* ebase = edt + (size_t)n * H_DIM * W_DIM;
    const int c0 = threadIdx.x * 4;

    // Rolling separable-Sobel state, per tensor:
    //   a[h] = x[h,w+1] - x[h,w-1]            (horizontal part of gx)
    //   b[h] = x[h,w-1] + 2x[h,w] + x[h,w+1]  (horizontal part of gy)
    // gx = a[h-1] + 2a[h] + a[h+1];  gy = b[h+1] - b[h-1]
    float sa0[4], sa1[4], sa2[4], sb0[4], sb1[4], sb2[4];
    float ea0[4], ea1[4], ea2[4], eb0[4], eb1[4], eb2[4];

    auto loadrow = [&](const float* base, int h, float* a, float* b) {
        if (h < 0 || h >= H_DIM) {
            #pragma unroll
            for (int i = 0; i < 4; ++i) { a[i] = 0.f; b[i] = 0.f; }
            return;
        }
        const float* row = base + (size_t)h * W_DIM;
        float4 v = *reinterpret_cast<const float4*>(row + c0);
        float xl = (c0 > 0)          ? row[c0 - 1] : 0.f;   // left halo (zero pad)
        float xr = (c0 + 4 < W_DIM)  ? row[c0 + 4] : 0.f;   // right halo
        float p0 = xl,  p1 = v.x, p2 = v.y, p3 = v.z, p4 = v.w, p5 = xr;
        a[0] = p2 - p0;  b[0] = p0 + 2.f*p1 + p2;
        a[1] = p3 - p1;  b[1] = p1 + 2.f*p2 + p3;
        a[2] = p4 - p2;  b[2] = p2 + 2.f*p3 + p4;
        a[3] = p5 - p3;  b[3] = p3 + 2.f*p4 + p5;
    };

    loadrow(sbase, r0 - 1, sa0, sb0);
    loadrow(ebase, r0 - 1, ea0, eb0);
    loadrow(sbase, r0,     sa1, sb1);
    loadrow(ebase, r0,     ea1, eb1);

    float acc = 0.f;
    for (int h = r0; h < r0 + ROWS; ++h) {
        loadrow(sbase, h + 1, sa2, sb2);
        loadrow(ebase, h + 1, ea2, eb2);
        #pragma unroll
        for (int i = 0; i < 4; ++i) {
            float sgx = sa0[i] + 2.f*sa1[i] + sa2[i];
            float sgy = sb2[i] - sb0[i];
            float es  = __builtin_amdgcn_sqrtf(sgx*sgx + sgy*sgy + EPS);
            float egx = ea0[i] + 2.f*ea1[i] + ea2[i];
            float egy = eb2[i] - eb0[i];
            float ee  = __builtin_amdgcn_sqrtf(egx*egx + egy*egy + EPS);
            float d   = ee - es;
            acc += d * d;
        }
        #pragma unroll
        for (int i = 0; i < 4; ++i) {
            sa0[i] = sa1[i]; sa1[i] = sa2[i];
            sb0[i] = sb1[i]; sb1[i] = sb2[i];
            ea0[i] = ea1[i]; ea1[i] = ea2[i];
            eb0[i] = eb1[i]; eb1[i] = eb2[i];
        }
    }

    // Block reduction: wave64 shuffle, then LDS across the 2 waves.
    #pragma unroll
    for (int off = 32; off > 0; off >>= 1)
        acc += __shfl_down(acc, off);
    __shared__ float wsum[TPB / 64];
    const int wid  = threadIdx.x >> 6;
    const int lane = threadIdx.x & 63;
    if (lane == 0) wsum[wid] = acc;
    __syncthreads();
    if (threadIdx.x == 0) {
        float tot = 0.f;
        #pragma unroll
        for (int i = 0; i < TPB / 64; ++i) tot += wsum[i];
        partial[blk] = tot;
    }
}

__global__ __launch_bounds__(256) void edge_loss_stage2(
    const float* __restrict__ partial, float* __restrict__ out, int nparts)
{
    double acc = 0.0;
    for (int i = threadIdx.x; i < nparts; i += 256)
        acc += (double)partial[i];
    #pragma unroll
    for (int off = 32; off > 0; off >>= 1)
        acc += __shfl_down(acc, off);
    __shared__ double wsum[4];
    const int wid  = threadIdx.x >> 6;
    const int lane = threadIdx.x & 63;
    if (lane == 0) wsum[wid] = acc;
    __syncthreads();
    if (threadIdx.x == 0) {
        double t = 0.0;
        #pragma unroll
        for (int i = 0; i < 4; ++i) t += wsum[i];
        out[0] = (float)(t / TOTAL_ELEMS);
    }
}

extern "C" void kernel_launch(void* const* d_in, const int* in_sizes, int n_in,
                              void* d_out, int out_size, void* d_ws, size_t ws_size,
                              hipStream_t stream) {
    const float* src = (const float*)d_in[0];  // source_latent
    const float* edt = (const float*)d_in[1];  // edited_latent
    // d_in[2]/d_in[3] are the fixed Sobel kernels; baked into the math above
    // (flip-sign ambiguity is irrelevant under the magnitude).
    float* out     = (float*)d_out;
    float* partial = (float*)d_ws;             // NBLK floats = 16 KB, overwritten every call

    edge_loss_stage1<<<dim3(NBLK), dim3(TPB), 0, stream>>>(src, edt, partial);
    edge_loss_stage2<<<dim3(1), dim3(256), 0, stream>>>(partial, out, NBLK);
}

// Round 3
// 52.464 us; speedup vs baseline: 1.0909x; 1.0909x over previous
//
#include <hip/hip_runtime.h>

// EdgeConsistencyLoss: mean((|∇edit| - |∇src|)^2) with Sobel 3x3, SAME zero pad.
// Shapes: [B=16, C=8, H=512, W=512] fp32 -> 128 independent 512x512 images.
//
// R1 lesson: occupancy 42->78% did NOT help (53->57us); halo bytes did hurt.
// R2: ROWS back to 32; software-pipelined row loads (issue row h+2 before
//     consuming row h+1) so VMEM latency hides under compute. Branchless
//     boundary handling (clamped row + zero mask) keeps prefetch unconditional.

#define EPS 1e-8f

constexpr int W_DIM  = 512;
constexpr int H_DIM  = 512;
constexpr int NIMG   = 128;           // B*C
constexpr int ROWS   = 32;            // rows per block chunk
constexpr int CHUNKS = H_DIM / ROWS;  // 16
constexpr int TPB    = 128;           // threads per block; 4 columns per thread
constexpr int NBLK   = NIMG * CHUNKS; // 2048
constexpr double TOTAL_ELEMS = 33554432.0; // 16*8*512*512

__global__ __launch_bounds__(TPB) void edge_loss_stage1(
    const float* __restrict__ src, const float* __restrict__ edt,
    float* __restrict__ partial)
{
    const int blk   = blockIdx.x;
    const int n     = blk / CHUNKS;
    const int chunk = blk % CHUNKS;
    const int r0    = chunk * ROWS;
    const float* sbase = src + (size_t)n * (H_DIM * W_DIM);
    const float* ebase = edt + (size_t)n * (H_DIM * W_DIM);
    const int c0 = threadIdx.x * 4;

    // Rolling separable-Sobel state:
    //   a[h] = x[h,w+1]-x[h,w-1];  b[h] = x[h,w-1]+2x[h,w]+x[h,w+1]
    //   gx = a[h-1]+2a[h]+a[h+1];  gy = b[h+1]-b[h-1]
    float sa0[4], sa1[4], sb0[4], sb1[4];
    float ea0[4], ea1[4], eb0[4], eb1[4];

    // Raw-pixel double buffers (6 px per tensor: left halo, 4, right halo).
    float spA[6], epA[6], spB[6], epB[6];
    float mA, mB;
    float acc = 0.f;

    // Issue loads for row h into (sp, ep); no dependent use here, so the
    // compiler leaves them in flight. Out-of-range rows load a clamped row
    // and are zeroed at consume time via mask m.
    auto issue = [&](int h, float* sp, float* ep, float& m) {
        int hc = h < 0 ? 0 : (h >= H_DIM ? H_DIM - 1 : h);
        m = (h >= 0 && h < H_DIM) ? 1.f : 0.f;
        const float* srow = sbase + (size_t)hc * W_DIM;
        const float* erow = ebase + (size_t)hc * W_DIM;
        float4 sv = *reinterpret_cast<const float4*>(srow + c0);
        float4 ev = *reinterpret_cast<const float4*>(erow + c0);
        float sl = (c0 > 0)         ? srow[c0 - 1] : 0.f;
        float sr = (c0 + 4 < W_DIM) ? srow[c0 + 4] : 0.f;
        float el = (c0 > 0)         ? erow[c0 - 1] : 0.f;
        float er = (c0 + 4 < W_DIM) ? erow[c0 + 4] : 0.f;
        sp[0]=sl; sp[1]=sv.x; sp[2]=sv.y; sp[3]=sv.z; sp[4]=sv.w; sp[5]=sr;
        ep[0]=el; ep[1]=ev.x; ep[2]=ev.y; ep[3]=ev.z; ep[4]=ev.w; ep[5]=er;
    };

    // Convert raw row (the h+1 row) to a2/b2 per column, compute output row h,
    // and shift the rolling state. Fused to minimize live registers.
    auto consume = [&](const float* sp, const float* ep, float m) {
        #pragma unroll
        for (int i = 0; i < 4; ++i) {
            float sa2 = m * (sp[i+2] - sp[i]);
            float sb2 = m * (sp[i] + 2.f*sp[i+1] + sp[i+2]);
            float ea2 = m * (ep[i+2] - ep[i]);
            float eb2 = m * (ep[i] + 2.f*ep[i+1] + ep[i+2]);
            float sgx = sa0[i] + 2.f*sa1[i] + sa2;
            float sgy = sb2 - sb0[i];
            float es  = __builtin_amdgcn_sqrtf(sgx*sgx + sgy*sgy + EPS);
            float egx = ea0[i] + 2.f*ea1[i] + ea2;
            float egy = eb2 - eb0[i];
            float ee  = __builtin_amdgcn_sqrtf(egx*egx + egy*egy + EPS);
            float d   = ee - es;
            acc += d * d;
            sa0[i] = sa1[i]; sa1[i] = sa2; sb0[i] = sb1[i]; sb1[i] = sb2;
            ea0[i] = ea1[i]; ea1[i] = ea2; eb0[i] = eb1[i]; eb1[i] = eb2;
        }
    };

    // Prologue: rows r0-1 and r0 into the rolling state; row r0+1 in flight.
    issue(r0 - 1, spA, epA, mA);
    {   // convert row r0-1 -> a0/b0
        #pragma unroll
        for (int i = 0; i < 4; ++i) {
            sa0[i] = mA * (spA[i+2] - spA[i]);
            sb0[i] = mA * (spA[i] + 2.f*spA[i+1] + spA[i+2]);
            ea0[i] = mA * (epA[i+2] - epA[i]);
            eb0[i] = mA * (epA[i] + 2.f*epA[i+1] + epA[i+2]);
        }
    }
    issue(r0, spB, epB, mB);
    {   // convert row r0 -> a1/b1
        #pragma unroll
        for (int i = 0; i < 4; ++i) {
            sa1[i] = mB * (spB[i+2] - spB[i]);
            sb1[i] = mB * (spB[i] + 2.f*spB[i+1] + spB[i+2]);
            ea1[i] = mB * (epB[i+2] - epB[i]);
            eb1[i] = mB * (epB[i] + 2.f*epB[i+1] + epB[i+2]);
        }
    }
    issue(r0 + 1, spA, epA, mA);   // row r0+1 in flight in buffer A

    // Main loop, 2 rows per iteration. Invariant at loop top:
    //   buffer A holds row h+1 (in flight); states hold rows h-1, h.
    for (int h = r0; h < r0 + ROWS; h += 2) {
        issue(h + 2, spB, epB, mB);       // prefetch next-next row
        consume(spA, epA, mA);            // compute output row h
        if (h + 3 <= r0 + ROWS)           // uniform; skip useless final prefetch
            issue(h + 3, spA, epA, mA);
        consume(spB, epB, mB);            // compute output row h+1
    }

    // Block reduction: wave64 shuffle, then LDS across the 2 waves.
    #pragma unroll
    for (int off = 32; off > 0; off >>= 1)
        acc += __shfl_down(acc, off);
    __shared__ float wsum[TPB / 64];
    const int wid  = threadIdx.x >> 6;
    const int lane = threadIdx.x & 63;
    if (lane == 0) wsum[wid] = acc;
    __syncthreads();
    if (threadIdx.x == 0) {
        float tot = 0.f;
        #pragma unroll
        for (int i = 0; i < TPB / 64; ++i) tot += wsum[i];
        partial[blk] = tot;
    }
}

__global__ __launch_bounds__(256) void edge_loss_stage2(
    const float* __restrict__ partial, float* __restrict__ out, int nparts)
{
    double acc = 0.0;
    for (int i = threadIdx.x; i < nparts; i += 256)
        acc += (double)partial[i];
    #pragma unroll
    for (int off = 32; off > 0; off >>= 1)
        acc += __shfl_down(acc, off);
    __shared__ double wsum[4];
    const int wid  = threadIdx.x >> 6;
    const int lane = threadIdx.x & 63;
    if (lane == 0) wsum[wid] = acc;
    __syncthreads();
    if (threadIdx.x == 0) {
        double t = 0.0;
        #pragma unroll
        for (int i = 0; i < 4; ++i) t += wsum[i];
        out[0] = (float)(t / TOTAL_ELEMS);
    }
}

extern "C" void kernel_launch(void* const* d_in, const int* in_sizes, int n_in,
                              void* d_out, int out_size, void* d_ws, size_t ws_size,
                              hipStream_t stream) {
    const float* src = (const float*)d_in[0];  // source_latent
    const float* edt = (const float*)d_in[1];  // edited_latent
    // d_in[2]/d_in[3] are the fixed Sobel kernels; baked into the math above
    // (flip-sign ambiguity is irrelevant under the magnitude).
    float* out     = (float*)d_out;
    float* partial = (float*)d_ws;             // NBLK floats = 8 KB, overwritten every call

    edge_loss_stage1<<<dim3(NBLK), dim3(TPB), 0, stream>>>(src, edt, partial);
    edge_loss_stage2<<<dim3(1), dim3(256), 0, stream>>>(partial, out, NBLK);
}